// Round 10
// baseline (407.336 us; speedup 1.0000x reference)
//
#include <hip/hip_runtime.h>
#include <hip/hip_bf16.h>
#include <math.h>

typedef __bf16 bf16s;
typedef __attribute__((ext_vector_type(8))) __bf16 bf16x8;
typedef __attribute__((ext_vector_type(4))) __bf16 bf16x4;
typedef __attribute__((ext_vector_type(4))) float f32x4;

#define B_   16
#define S_   1024
#define H_   768
#define T_   64
#define L_   4
#define LE_  32
#define NPAD 4096
#define BS   (B_*S_)    // 16384
#define BNR  (B_*NPAD)  // 65536 rows of X
#define N3   (3*H_)     // 2304

static __device__ __forceinline__ void gload_lds16(const void* g, void* l) {
  __builtin_amdgcn_global_load_lds(
      (const __attribute__((address_space(1))) void*)g,
      (__attribute__((address_space(3))) void*)l, 16, 0, 0);
}

// ---------------- span construction (1 block) ----------------
__global__ __launch_bounds__(1024) void k_build_spans(
    const int* __restrict__ text_mask,   // row 0 used
    int* __restrict__ R, int* __restrict__ pos, int* __restrict__ spoff,
    int* __restrict__ starts, int* __restrict__ ends, int* __restrict__ lens,
    int* __restrict__ meta)
{
  __shared__ int buf[S_];
  int t = threadIdx.x;
  int m = text_mask[t] ? 1 : 0;
  buf[t] = m;
  __syncthreads();
  for (int off = 1; off < S_; off <<= 1) {
    int v = buf[t];
    if (t >= off) v += buf[t - off];
    __syncthreads();
    buf[t] = v;
    __syncthreads();
  }
  int incl = buf[t];
  R[t] = incl;
  if (m) pos[incl - 1] = t;
  int n = buf[S_ - 1];
  __syncthreads();
  int cnt = (t < n) ? min(L_, n - t) : 0;
  buf[t] = cnt;
  __syncthreads();
  for (int off = 1; off < S_; off <<= 1) {
    int v = buf[t];
    if (t >= off) v += buf[t - off];
    __syncthreads();
    buf[t] = v;
    __syncthreads();
  }
  int inc2 = buf[t];
  int base = inc2 - cnt;
  spoff[t] = base;
  if (t == 0) { meta[0] = buf[S_ - 1]; meta[1] = n; }
  __syncthreads();
  if (t < n) {
    int p0 = pos[t];
    for (int k = 0; k < cnt; k++) {
      starts[base + k] = p0;
      ends[base + k]   = pos[t + k];
      lens[base + k]   = k + 1;
    }
  }
}

// ---------------- fused prep: casts + transposes + LT + topicn ----------------
__global__ __launch_bounds__(256) void k_prep(
    const float* __restrict__ hid, bf16s* __restrict__ hidb,
    const float* __restrict__ W1, bf16s* __restrict__ wbt,
    const float* __restrict__ W2, bf16s* __restrict__ w2t, bf16s* __restrict__ w2c,
    const float* __restrict__ lemb, float* __restrict__ LT,
    const float* __restrict__ TH, const float* __restrict__ b2,
    bf16s* __restrict__ TN, float* __restrict__ cvec)
{
  __shared__ float tile[64][65];
  __shared__ float red[256];
  int bid = blockIdx.x;
  int t = threadIdx.x;
  if (bid < 12288) {
    int i = bid * 256 + t;           // BS*H/4 groups
    f32x4 v = ((const f32x4*)hid)[i];
    bf16x4 o;
    o[0] = (__bf16)v[0]; o[1] = (__bf16)v[1]; o[2] = (__bf16)v[2]; o[3] = (__bf16)v[3];
    ((bf16x4*)hidb)[i] = o;
  } else if (bid < 12864) {
    int local = bid - 12288;
    int c = local / 144, rem = local % 144;
    const float* in = (c < 3) ? (W1 + (size_t)c * H_ * H_) : W2;
    bf16s* out = (c < 3) ? (wbt + (size_t)c * H_ * H_) : w2t;
    int r0 = (rem / 12) * 64, c0 = (rem % 12) * 64;
    int tr = t >> 4, tc = (t & 15) * 4;
#pragma unroll
    for (int i = 0; i < 4; i++) {
      int row = tr + i * 16;
      f32x4 v = *(const f32x4*)(in + (long)(r0 + row) * H_ + c0 + tc);
      tile[row][tc+0] = v[0]; tile[row][tc+1] = v[1];
      tile[row][tc+2] = v[2]; tile[row][tc+3] = v[3];
    }
    __syncthreads();
#pragma unroll
    for (int i = 0; i < 4; i++) {
      int cc = tr + i * 16;
      bf16x4 o;
      o[0] = (__bf16)tile[tc+0][cc]; o[1] = (__bf16)tile[tc+1][cc];
      o[2] = (__bf16)tile[tc+2][cc]; o[3] = (__bf16)tile[tc+3][cc];
      *(bf16x4*)(out + (long)(c0 + cc) * H_ + r0 + tc) = o;
    }
  } else if (bid < 13440) {
    int i = (bid - 12864) * 256 + t;   // H*H/4 groups
    f32x4 v = ((const f32x4*)W2)[i];
    bf16x4 o;
    o[0] = (__bf16)v[0]; o[1] = (__bf16)v[1]; o[2] = (__bf16)v[2]; o[3] = (__bf16)v[3];
    ((bf16x4*)w2c)[i] = o;
  } else if (bid < 13455) {
    int idx = (bid - 13440) * 256 + t;
    if (idx < (L_ + 1) * H_) {
      int l = idx / H_, h = idx % H_;
      float acc = 0.f;
#pragma unroll
      for (int e = 0; e < LE_; e++) acc += lemb[l * LE_ + e] * W1[(long)(N3 + e) * H_ + h];
      LT[idx] = acc;
    }
  } else {
    int r = bid - 13455;               // topic row 0..1023
    const float* row = TH + (long)r * H_;
    float v0 = row[t], v1 = row[t + 256], v2 = row[t + 512];
    red[t] = v0 * v0 + v1 * v1 + v2 * v2;
    __syncthreads();
    for (int off = 128; off; off >>= 1) {
      if (t < off) red[t] += red[t + off];
      __syncthreads();
    }
    float rn = 1.0f / fmaxf(sqrtf(red[0]), 1e-12f);
    bf16s* o = TN + (long)r * H_;
    o[t] = (__bf16)(v0 * rn); o[t + 256] = (__bf16)(v1 * rn); o[t + 512] = (__bf16)(v2 * rn);
    __syncthreads();
    red[t] = v0 * b2[t] + v1 * b2[t + 256] + v2 * b2[t + 512];
    __syncthreads();
    for (int off = 128; off; off >>= 1) {
      if (t < off) red[t] += red[t + off];
      __syncthreads();
    }
    if (t == 0) cvec[r] = red[0] * rn;
  }
}

// ====== single-tile 8-phase GEMM core macros (BK=64, r5-proven) ======
#define BKT 64
#define STG1_A(kt_, h_) do { \
    const bf16s* s_ = gA + (long)(h_) * 128 * K + (long)(kt_) * BKT; \
    char* d_ = sA + ((kt_) & 1) * 32768 + (h_) * 16384 + wid * 1024; \
    gload_lds16(s_, d_); \
    gload_lds16(s_ + 64L * K, d_ + 8192); \
  } while (0)
#define STG1_B(kt_, h_) do { \
    const bf16s* s_ = gB + (long)(h_) * 128 * K + (long)(kt_) * BKT; \
    char* d_ = sB + ((kt_) & 1) * 32768 + (h_) * 16384 + wid * 1024; \
    gload_lds16(s_, d_); \
    gload_lds16(s_ + 64L * K, d_ + 8192); \
  } while (0)
#define MFMA_Q(AF_, FR0_, FC_) do { \
    _Pragma("unroll") \
    for (int f_ = 0; f_ < 4; ++f_) { \
      acc[FR0_+f_][FC_] = __builtin_amdgcn_mfma_f32_16x16x32_bf16(bfv[FC_][0], AF_[f_][0], acc[FR0_+f_][FC_], 0, 0, 0); \
      acc[FR0_+f_][FC_] = __builtin_amdgcn_mfma_f32_16x16x32_bf16(bfv[FC_][1], AF_[f_][1], acc[FR0_+f_][FC_], 0, 0, 0); \
    } } while (0)
#define PH_PRE()  __builtin_amdgcn_s_barrier(); \
                  asm volatile("s_waitcnt lgkmcnt(0)" ::: "memory"); \
                  __builtin_amdgcn_s_setprio(1)
#define PH_POST() __builtin_amdgcn_s_setprio(0); \
                  __builtin_amdgcn_s_barrier()

// ---- GEMM1 + U-GEMM (r9 config; 512 blocks, blocks 0..75 run 2 items) ----
__global__ __launch_bounds__(512, 2) void k_gemm8p(
    const bf16s* __restrict__ Ah, const bf16s* __restrict__ Bth, bf16s* __restrict__ Ch,
    const bf16s* __restrict__ Au, const bf16s* __restrict__ Btu, bf16s* __restrict__ Cu)
{
  __shared__ __align__(16) char sA[65536];
  __shared__ __align__(16) char sB[65536];
  const int K = H_;

  int tid = threadIdx.x;
  int wid = tid >> 6, l = tid & 63;
  int wr = wid >> 2, wc = wid & 3;          // 2x4 waves; wave tile 128x64
  int srow = tid >> 3;
  int sslot = (tid & 7) ^ (srow & 7);

  const char* aP0 = sA + wr * 16384;
  const char* aP1 = aP0 + 32768;
  const char* bP0 = sB + (wc >> 1) * 16384 + (wc & 1) * 8192;
  const char* bP1 = bP0 + 32768;
  int lrow = (l & 15) * 128;
  int ls0 = (((l >> 4) ^ (l & 7)) * 16);

  int nseg = (blockIdx.x < 76) ? 2 : 1;
#pragma unroll 1
  for (int seg = 0; seg < nseg; ++seg) {
    int raw = (seg == 0) ? blockIdx.x : 512 + blockIdx.x;
    const int nwg = 588;
    int q = nwg >> 3, rr = nwg & 7;
    int xcd = raw & 7, ix = raw >> 3;
    int nid = (xcd < rr ? xcd * (q + 1) : rr * (q + 1) + (xcd - rr) * q) + ix;

    const bf16s *A, *Bt;
    bf16s* C;
    long a0, b0;
    int NN;
    if (nid < 576) {
      A = Ah; Bt = Bth; C = Ch; NN = N3;
      a0 = (long)(nid / 9) * 256;
      b0 = (long)(nid % 9) * 256;
    } else {
      int u = nid - 576;
      A = Au; Bt = Btu; C = Cu; NN = H_;
      a0 = (long)(u / 3) * 256;
      b0 = (long)(u % 3) * 256;
    }
    const bf16s* gA = A + (a0 + srow) * (long)K + sslot * 8;
    const bf16s* gB = Bt + (b0 + srow) * (long)K + sslot * 8;

    f32x4 acc[8][4];
#pragma unroll
    for (int i = 0; i < 8; i++)
#pragma unroll
      for (int j = 0; j < 4; j++) acc[i][j] = (f32x4){0.f, 0.f, 0.f, 0.f};

    STG1_B(0, 0); STG1_B(0, 1); STG1_A(0, 0); STG1_A(0, 1);
    STG1_B(1, 0); STG1_B(1, 1); STG1_A(1, 0);
    asm volatile("s_waitcnt vmcnt(6)" ::: "memory");
    __builtin_amdgcn_s_barrier();

    for (int it = 0; it < 6; ++it) {
      int t0 = 2 * it, t1 = t0 + 1;
      bool nl = (it != 5);
      bf16x8 af0[4][2], af1[4][2], bfv[4][2];

#pragma unroll
      for (int f = 0; f < 4; ++f) {
        af0[f][0] = *(const bf16x8*)(aP0 + f * 2048 + lrow + ls0);
        af0[f][1] = *(const bf16x8*)(aP0 + f * 2048 + lrow + (ls0 ^ 64));
      }
#pragma unroll
      for (int c = 0; c < 4; ++c) {
        bfv[c][0] = *(const bf16x8*)(bP0 + c * 2048 + lrow + ls0);
        bfv[c][1] = *(const bf16x8*)(bP0 + c * 2048 + lrow + (ls0 ^ 64));
      }
      STG1_A(t1, 1);
      PH_PRE();
      MFMA_Q(af0, 0, 0); MFMA_Q(af0, 0, 1);
      PH_POST();

      if (nl) STG1_B(t0 + 2, 0);
      PH_PRE();
      MFMA_Q(af0, 0, 2); MFMA_Q(af0, 0, 3);
      PH_POST();

#pragma unroll
      for (int f = 0; f < 4; ++f) {
        af1[f][0] = *(const bf16x8*)(aP0 + (f + 4) * 2048 + lrow + ls0);
        af1[f][1] = *(const bf16x8*)(aP0 + (f + 4) * 2048 + lrow + (ls0 ^ 64));
      }
      if (nl) STG1_B(t0 + 2, 1);
      PH_PRE();
      MFMA_Q(af1, 4, 0); MFMA_Q(af1, 4, 1);
      PH_POST();

      if (nl) { STG1_A(t0 + 2, 0); asm volatile("s_waitcnt vmcnt(6)" ::: "memory"); }
      else    { asm volatile("s_waitcnt vmcnt(0)" ::: "memory"); }
      PH_PRE();
      MFMA_Q(af1, 4, 2); MFMA_Q(af1, 4, 3);
      PH_POST();

#pragma unroll
      for (int f = 0; f < 4; ++f) {
        af0[f][0] = *(const bf16x8*)(aP1 + f * 2048 + lrow + ls0);
        af0[f][1] = *(const bf16x8*)(aP1 + f * 2048 + lrow + (ls0 ^ 64));
      }
#pragma unroll
      for (int c = 0; c < 4; ++c) {
        bfv[c][0] = *(const bf16x8*)(bP1 + c * 2048 + lrow + ls0);
        bfv[c][1] = *(const bf16x8*)(bP1 + c * 2048 + lrow + (ls0 ^ 64));
      }
      if (nl) STG1_A(t0 + 2, 1);
      PH_PRE();
      MFMA_Q(af0, 0, 0); MFMA_Q(af0, 0, 1);
      PH_POST();

      if (nl) STG1_B(t1 + 2, 0);
      PH_PRE();
      MFMA_Q(af0, 0, 2); MFMA_Q(af0, 0, 3);
      PH_POST();

#pragma unroll
      for (int f = 0; f < 4; ++f) {
        af1[f][0] = *(const bf16x8*)(aP1 + (f + 4) * 2048 + lrow + ls0);
        af1[f][1] = *(const bf16x8*)(aP1 + (f + 4) * 2048 + lrow + (ls0 ^ 64));
      }
      if (nl) STG1_B(t1 + 2, 1);
      PH_PRE();
      MFMA_Q(af1, 4, 0); MFMA_Q(af1, 4, 1);
      PH_POST();

      if (nl) { STG1_A(t1 + 2, 0); asm volatile("s_waitcnt vmcnt(6)" ::: "memory"); }
      else    { asm volatile("s_waitcnt vmcnt(0)" ::: "memory"); }
      PH_PRE();
      MFMA_Q(af1, 4, 2); MFMA_Q(af1, 4, 3);
      PH_POST();
    }

#pragma unroll
    for (int fc = 0; fc < 4; fc++) {
      long n0 = b0 + wc * 64 + fc * 16 + (l >> 4) * 4;
#pragma unroll
      for (int fr = 0; fr < 8; fr++) {
        long mrow = a0 + wr * 128 + fr * 16 + (l & 15);
        bf16x4 o;
#pragma unroll
        for (int r = 0; r < 4; r++) o[r] = (__bf16)acc[fr][fc][r];
        *(bf16x4*)(C + mrow * (long)NN + n0) = o;
      }
    }
  }
}

// ====== NEW: norm-only GEMM, 128x256 tile, BK=32, 48KB LDS, 2 blocks/CU ======
// ssbuf[row] = sum over 768 cols of (X@W2^T + b2)^2. 512 blocks x 128 rows,
// 3 chained column-segments (no atomics). 4-phase/2-K-tile counted vmcnt(3).
// LDS: sA [2 buf][128 rows][4 x 16B slots] = 16KB; sB [2 buf][2 half][128][4] = 32KB.
// Swizzle: stored slot = logical ^ ((row>>1)&3), inverse-applied on gload source.
__global__ __launch_bounds__(512, 4) void k_gemmnorm(
    const bf16s* __restrict__ Ax, const bf16s* __restrict__ Btw,
    const float* __restrict__ bias, float* __restrict__ ssbuf)
{
  __shared__ __align__(16) char sA[16384];
  __shared__ __align__(16) char sB[32768];
  const int K = H_;
  int bid = blockIdx.x;
  int nid = (bid & 7) * 64 + (bid >> 3);    // bijective over 512
  long a0 = (long)nid * 128;
  int tid = threadIdx.x;
  int wid = tid >> 6, l = tid & 63;
  int wr = wid >> 2, wc = wid & 3;          // 2x4 waves; wave tile 64x64
  int srow = tid >> 2;                      // 0..127
  int sslot = (tid & 3) ^ ((srow >> 1) & 3);
  const bf16s* gA = Ax + (a0 + srow) * (long)K + sslot * 8;
  const bf16s* gB = Btw + (long)srow * K + sslot * 8;

#define SGA(kt_) \
    gload_lds16(gA + (long)(kt_) * 32, sA + ((kt_) & 1) * 8192 + tid * 16)
#define SGB(ct_, kt_, h_) \
    gload_lds16(gB + ((long)(ct_) * 256 + (h_) * 128) * K + (long)(kt_) * 32, \
                sB + ((kt_) & 1) * 16384 + (h_) * 8192 + tid * 16)

  const char* aB = sA + wr * 4096;          // buf0; buf1 = +8192
  const char* bB = sB + (wc >> 1) * 8192 + (wc & 1) * 4096;  // buf0; buf1 = +16384
  int lrow = (l & 15) * 64;
  int ls0 = ((l >> 4) ^ (((l & 15) >> 1) & 3)) * 16;

  f32x4 acc[4][4];
#pragma unroll
  for (int i = 0; i < 4; i++)
#pragma unroll
    for (int j = 0; j < 4; j++) acc[i][j] = (f32x4){0.f, 0.f, 0.f, 0.f};
  float ssp[4] = {0.f, 0.f, 0.f, 0.f};

  // prologue: tile0 {B0,B1,A}, tile1 {B0,B1,A} -> 6 loads; wait tile0 (3 oldest)
  SGB(0, 0, 0); SGB(0, 0, 1); SGA(0);
  SGB(0, 1, 0); SGB(0, 1, 1); SGA(1);
  asm volatile("s_waitcnt vmcnt(3)" ::: "memory");
  __builtin_amdgcn_s_barrier();

  for (int s = 0; s < 3; ++s) {
    for (int it = 0; it < 12; ++it) {
      int t0 = 2 * it;
      bool nl = !(s == 2 && it == 11);
      int ctn = (it == 11) ? s + 1 : s;
      int kn0 = (it == 11) ? 0 : t0 + 2;
      int kn1 = kn0 + 1;
      bf16x8 af[4], bfv[4];

      // ---- phase 1: read buf0 frags (tile t0); MFMA fc0,1
#pragma unroll
      for (int f = 0; f < 4; ++f) af[f] = *(const bf16x8*)(aB + f * 1024 + lrow + ls0);
#pragma unroll
      for (int c = 0; c < 4; ++c) bfv[c] = *(const bf16x8*)(bB + c * 1024 + lrow + ls0);
      PH_PRE();
#pragma unroll
      for (int f = 0; f < 4; ++f) {
        acc[f][0] = __builtin_amdgcn_mfma_f32_16x16x32_bf16(bfv[0], af[f], acc[f][0], 0, 0, 0);
        acc[f][1] = __builtin_amdgcn_mfma_f32_16x16x32_bf16(bfv[1], af[f], acc[f][1], 0, 0, 0);
      }
      PH_POST();

      // ---- phase 2: stage next tile (kn0) into buf0; vmcnt(3) [tile t1 landed]
      if (nl) { SGB(ctn, kn0, 0); SGB(ctn, kn0, 1); SGA(kn0);
                asm volatile("s_waitcnt vmcnt(3)" ::: "memory"); }
      else    { asm volatile("s_waitcnt vmcnt(0)" ::: "memory"); }
      PH_PRE();
#pragma unroll
      for (int f = 0; f < 4; ++f) {
        acc[f][2] = __builtin_amdgcn_mfma_f32_16x16x32_bf16(bfv[2], af[f], acc[f][2], 0, 0, 0);
        acc[f][3] = __builtin_amdgcn_mfma_f32_16x16x32_bf16(bfv[3], af[f], acc[f][3], 0, 0, 0);
      }
      PH_POST();

      // ---- phase 3: read buf1 frags (tile t1); MFMA fc0,1
#pragma unroll
      for (int f = 0; f < 4; ++f) af[f] = *(const bf16x8*)(aB + 8192 + f * 1024 + lrow + ls0);
#pragma unroll
      for (int c = 0; c < 4; ++c) bfv[c] = *(const bf16x8*)(bB + 16384 + c * 1024 + lrow + ls0);
      PH_PRE();
#pragma unroll
      for (int f = 0; f < 4; ++f) {
        acc[f][0] = __builtin_amdgcn_mfma_f32_16x16x32_bf16(bfv[0], af[f], acc[f][0], 0, 0, 0);
        acc[f][1] = __builtin_amdgcn_mfma_f32_16x16x32_bf16(bfv[1], af[f], acc[f][1], 0, 0, 0);
      }
      PH_POST();

      // ---- phase 4: stage tile kn1 into buf1; vmcnt(3) [tile kn0 landed for next ph1]
      if (nl) { SGB(ctn, kn1, 0); SGB(ctn, kn1, 1); SGA(kn1);
                asm volatile("s_waitcnt vmcnt(3)" ::: "memory"); }
      else    { asm volatile("s_waitcnt vmcnt(0)" ::: "memory"); }
      PH_PRE();
#pragma unroll
      for (int f = 0; f < 4; ++f) {
        acc[f][2] = __builtin_amdgcn_mfma_f32_16x16x32_bf16(bfv[2], af[f], acc[f][2], 0, 0, 0);
        acc[f][3] = __builtin_amdgcn_mfma_f32_16x16x32_bf16(bfv[3], af[f], acc[f][3], 0, 0, 0);
      }
      PH_POST();
    }
    // ---- per-segment epilogue: accumulate (acc+bias)^2 into ssp; reset acc
    {
      f32x4 bb[4];
#pragma unroll
      for (int fc = 0; fc < 4; ++fc)
        bb[fc] = *(const f32x4*)(bias + s * 256 + wc * 64 + fc * 16 + (l >> 4) * 4);
#pragma unroll
      for (int f = 0; f < 4; ++f) {
        float p = 0.f;
#pragma unroll
        for (int fc = 0; fc < 4; ++fc) {
#pragma unroll
          for (int r = 0; r < 4; ++r) {
            float y = acc[f][fc][r] + bb[fc][r];
            p += y * y;
          }
          acc[f][fc] = (f32x4){0.f, 0.f, 0.f, 0.f};
        }
        ssp[f] += p;
      }
    }
  }

  // cross-wave reduction: 4 wc-waves hold partial column sums for same rows.
  float* sred = (float*)sA;   // pipeline drained; sA dead
#pragma unroll
  for (int f = 0; f < 4; ++f) {
    float p = ssp[f];
    p += __shfl_xor(p, 16);
    p += __shfl_xor(p, 32);
    if (l < 16) sred[wc * 128 + wr * 64 + f * 16 + l] = p;
  }
  __syncthreads();
  if (tid < 128) {
    ssbuf[a0 + tid] = sred[tid] + sred[128 + tid] + sred[256 + tid] + sred[384 + tid];
  }
#undef SGA
#undef SGB
}

#undef STG1_A
#undef STG1_B
#undef MFMA_Q
#undef PH_PRE
#undef PH_POST

// ---------------- z1: per (batch, start-pos) group, running-sum mean ----------
__global__ __launch_bounds__(192) void k_z1(
    const bf16s* __restrict__ P,
    const float* __restrict__ LT, const float* __restrict__ b1,
    const int* __restrict__ pos, const int* __restrict__ spoff,
    const int* __restrict__ meta, bf16s* __restrict__ X)
{
  int bid = blockIdx.x;
  int t = threadIdx.x;            // 0..191
  int h = t * 4;
  if (bid < BS) {
    int b = bid >> 10, i = bid & (S_ - 1);
    int n = meta[1];
    if (i >= n) return;
    int cnt = min(L_, n - i);
    int sa = pos[i];
    int base = spoff[i];
    const bf16s* Pb = P + (long)b * S_ * N3;
    bf16x4 vs = *(const bf16x4*)(Pb + (long)sa * N3 + h);
    f32x4 bb = *(const f32x4*)(b1 + h);
    float run[4] = {0.f, 0.f, 0.f, 0.f};
    int r = sa;
    for (int k = 0; k < cnt; ++k) {
      int se = pos[i + k];
      for (; r <= se; ++r) {
        bf16x4 vm = *(const bf16x4*)(Pb + (long)r * N3 + 2 * H_ + h);
#pragma unroll
        for (int j = 0; j < 4; j++) run[j] += (float)vm[j];
      }
      bf16x4 ve = *(const bf16x4*)(Pb + (long)se * N3 + H_ + h);
      f32x4 lt = *(const f32x4*)(LT + (long)(k + 1) * H_ + h);
      float il = 1.0f / (float)(k + 1);
      bf16x4 o;
#pragma unroll
      for (int j = 0; j < 4; j++) {
        float x = (float)vs[j] + (float)ve[j] + run[j] * il + lt[j] + bb[j];
        float g = 0.5f * x * (1.0f + erff(x * 0.70710678118654752f));
        o[j] = (__bf16)g;
      }
      *(bf16x4*)(X + ((long)b * NPAD + base + k) * H_ + h) = o;
    }
  } else {
    // zero-fill pad rows [N, NPAD) across all batches (grid-stride)
    int N = meta[0];
    int pad = NPAD - N;
    if (pad <= 0) return;
    long total = (long)B_ * pad * 192;
    for (long idx = (long)(bid - BS) * 192 + t; idx < total; idx += 512L * 192) {
      int h4 = (int)(idx % 192);
      long rrw = idx / 192;
      int pr = (int)(rrw % pad);
      int bb2 = (int)(rrw / pad);
      bf16x4 z; z[0] = z[1] = z[2] = z[3] = (__bf16)0.f;
      *(bf16x4*)(X + ((long)bb2 * NPAD + N + pr) * H_ + h4 * 4) = z;
    }
  }
}

// ------- sim from X: scores[b,n] = max_t (U[t]·X_n + c[t]) * rsqrt(ss[n]) ----
__global__ __launch_bounds__(256) void k_simx(
    const bf16s* __restrict__ X, const bf16s* __restrict__ U,
    const float* __restrict__ cvec, const float* __restrict__ ssbuf,
    const int* __restrict__ tmask, float* __restrict__ scores)
{
  int b = blockIdx.y;
  int wid = threadIdx.x >> 6, l = threadIdx.x & 63;
  int st = blockIdx.x * 4 + wid;
  int span = st * 16 + (l & 15);
  const bf16s* xrow = X + (long)(b * NPAD + span) * H_ + (l >> 4) * 8;
  const bf16s* ubase = U + (long)b * T_ * H_ + (l >> 4) * 8;
  f32x4 acc[4];
#pragma unroll
  for (int tt = 0; tt < 4; tt++) acc[tt] = (f32x4){0.f, 0.f, 0.f, 0.f};
  for (int kk = 0; kk < H_ / 32; kk++) {
    bf16x8 av = *(const bf16x8*)(xrow + kk * 32);
#pragma unroll
    for (int tt = 0; tt < 4; tt++) {
      bf16x8 bv = *(const bf16x8*)(ubase + (long)(tt * 16 + (l & 15)) * H_ + kk * 32);
      acc[tt] = __builtin_amdgcn_mfma_f32_16x16x32_bf16(av, bv, acc[tt], 0, 0, 0);
    }
  }
  const int* tm = tmask + b * T_;
  bool msk[4];
  float cv[4];
#pragma unroll
  for (int tt = 0; tt < 4; tt++) {
    int tcol = tt * 16 + (l & 15);
    msk[tt] = tm[tcol] != 0;
    cv[tt] = cvec[b * T_ + tcol];
  }
  float best[4];
#pragma unroll
  for (int r = 0; r < 4; r++) {
    float v = -INFINITY;
#pragma unroll
    for (int tt = 0; tt < 4; tt++) if (msk[tt]) v = fmaxf(v, acc[tt][r] + cv[tt]);
    best[r] = v;
  }
#pragma unroll
  for (int off = 8; off; off >>= 1)
#pragma unroll
    for (int r = 0; r < 4; r++) best[r] = fmaxf(best[r], __shfl_xor(best[r], off));
  if ((l & 15) == 0) {
    int srow = st * 16 + (l >> 4) * 4;
#pragma unroll
    for (int r = 0; r < 4; r++) {
      float ss = ssbuf[b * NPAD + srow + r];
      scores[b * NPAD + srow + r] = best[r] / fmaxf(sqrtf(ss), 1e-12f);
    }
  }
}

// ---------------- token max ----------------
__global__ __launch_bounds__(256) void k_token(
    const int* __restrict__ text_mask,
    const int* __restrict__ R, const int* __restrict__ spoff,
    const int* __restrict__ meta, const float* __restrict__ scores,
    float* __restrict__ out)
{
  int idx = blockIdx.x * 256 + threadIdx.x;  // B*S
  int s = idx % S_, b = idx / S_;
  if (!text_mask[b * S_ + s]) { out[idx] = -INFINITY; return; }
  int n = meta[1];
  int r1 = R[s];
  int le = r1 - 1;                         // largest i with pos[i] <= s
  int ge = text_mask[s] ? (r1 - 1) : r1;   // smallest j with pos[j] >= s (row 0)
  float best = -INFINITY;
  if (le >= 0 && ge < n) {
    int i0 = max(0, ge - (L_ - 1));
    for (int i = i0; i <= le; i++) {
      int jmax = min(i + L_ - 1, n - 1);
      int off = spoff[i];
      for (int j = max(i, ge); j <= jmax; j++)
        best = fmaxf(best, scores[b * NPAD + off + (j - i)]);
    }
  }
  out[idx] = best;
}

// ---------------- ws-too-small sentinel ----------------
__global__ __launch_bounds__(256) void k_sentinel(float* __restrict__ out) {
  int i = blockIdx.x * 256 + threadIdx.x;
  if (i < BS) out[i] = 12345.0f;
}

// ---------------- launch ----------------
extern "C" void kernel_launch(void* const* d_in, const int* in_sizes, int n_in,
                              void* d_out, int out_size, void* d_ws, size_t ws_size,
                              hipStream_t stream) {
  const float* hid = (const float*)d_in[0];
  const float* th  = (const float*)d_in[1];
  const int* tmask = (const int*)d_in[2];
  const int* xmask = (const int*)d_in[3];
  const float* lemb = (const float*)d_in[4];
  const float* W1   = (const float*)d_in[5];
  const float* b1   = (const float*)d_in[6];
  const float* W2   = (const float*)d_in[7];
  const float* b2   = (const float*)d_in[8];
  float* out = (float*)d_out;

  char* w = (char*)d_ws;
  auto alloc = [&](size_t bytes) {
    char* p = w; w += (bytes + 255) & ~(size_t)255; return p;
  };
  // small buffers (~10 MB)
  bf16s* wbt   = (bf16s*)alloc((size_t)N3 * H_ * 2);
  bf16s* w2t   = (bf16s*)alloc((size_t)H_ * H_ * 2);
  bf16s* w2c   = (bf16s*)alloc((size_t)H_ * H_ * 2);
  float* LT    = (float*)alloc((size_t)(L_ + 1) * H_ * 4);
  bf16s* topn  = (bf16s*)alloc((size_t)B_ * T_ * H_ * 2);
  bf16s* U     = (bf16s*)alloc((size_t)B_ * T_ * H_ * 2);
  float* cvec  = (float*)alloc((size_t)B_ * T_ * 4);
  float* ssbuf = (float*)alloc((size_t)BNR * 4);
  float* scores= (float*)alloc((size_t)B_ * NPAD * 4);
  int* R       = (int*)alloc(S_ * 4);
  int* pos     = (int*)alloc(S_ * 4);
  int* spoff   = (int*)alloc(S_ * 4);
  int* starts  = (int*)alloc(NPAD * 4);
  int* ends    = (int*)alloc(NPAD * 4);
  int* lens    = (int*)alloc(NPAD * 4);
  int* meta    = (int*)alloc(2 * 4);
  // region A: [hidb | P] (100.66 MB)
  char* regionA = alloc((size_t)BS * H_ * 2 + (size_t)BS * N3 * 2);
  bf16s* hidb  = (bf16s*)regionA;
  bf16s* P     = (bf16s*)(regionA + (size_t)BS * H_ * 2);
  // region B: X (100.66 MB)
  bf16s* X     = (bf16s*)alloc((size_t)BNR * H_ * 2);

  size_t required = (size_t)(w - (char*)d_ws);
  if (required > ws_size) {
    k_sentinel<<<(BS + 255) / 256, 256, 0, stream>>>(out);
    return;
  }

  k_build_spans<<<1, 1024, 0, stream>>>(xmask, R, pos, spoff, starts, ends, lens, meta);
  k_prep<<<14479, 256, 0, stream>>>(hid, hidb, W1, wbt, W2, w2t, w2c,
                                    lemb, LT, th, b2, topn, cvec);

  // GEMM1 (576 P-tiles) + U-GEMM (12 tiles) over 512 blocks, <=2 items each
  k_gemm8p<<<512, 512, 0, stream>>>(hidb, wbt, P, topn, w2c, U);

  k_z1<<<BS + 512, 192, 0, stream>>>(P, LT, b1, pos, spoff, meta, X);

  // norm-only GEMM2: 512 blocks (128 rows each), BK=32, 2 blocks/CU
  k_gemmnorm<<<512, 512, 0, stream>>>(X, w2t, b2, ssbuf);

  k_simx<<<dim3(NPAD / 64, B_), 256, 0, stream>>>(X, U, cvec, ssbuf, tmask, scores);
  k_token<<<(B_ * S_) / 256, 256, 0, stream>>>(xmask, R, spoff, meta, scores, out);
  (void)in_sizes; (void)n_in; (void)out_size;
}

// Round 11
// 303.382 us; speedup vs baseline: 1.3427x; 1.3427x over previous
//
#include <hip/hip_runtime.h>
#include <hip/hip_bf16.h>
#include <math.h>

typedef __bf16 bf16s;
typedef __attribute__((ext_vector_type(8))) __bf16 bf16x8;
typedef __attribute__((ext_vector_type(4))) __bf16 bf16x4;
typedef __attribute__((ext_vector_type(4))) float f32x4;

#define B_   16
#define S_   1024
#define H_   768
#define T_   64
#define L_   4
#define LE_  32
#define NPAD 4096
#define BS   (B_*S_)    // 16384
#define BNR  (B_*NPAD)  // 65536 rows of X
#define N3   (3*H_)     // 2304

static __device__ __forceinline__ void gload_lds16(const void* g, void* l) {
  __builtin_amdgcn_global_load_lds(
      (const __attribute__((address_space(1))) void*)g,
      (__attribute__((address_space(3))) void*)l, 16, 0, 0);
}

// ---------------- span construction (1 block) ----------------
__global__ __launch_bounds__(1024) void k_build_spans(
    const int* __restrict__ text_mask,   // row 0 used
    int* __restrict__ R, int* __restrict__ pos, int* __restrict__ spoff,
    int* __restrict__ starts, int* __restrict__ ends, int* __restrict__ lens,
    int* __restrict__ meta)
{
  __shared__ int buf[S_];
  int t = threadIdx.x;
  int m = text_mask[t] ? 1 : 0;
  buf[t] = m;
  __syncthreads();
  for (int off = 1; off < S_; off <<= 1) {
    int v = buf[t];
    if (t >= off) v += buf[t - off];
    __syncthreads();
    buf[t] = v;
    __syncthreads();
  }
  int incl = buf[t];
  R[t] = incl;
  if (m) pos[incl - 1] = t;
  int n = buf[S_ - 1];
  __syncthreads();
  int cnt = (t < n) ? min(L_, n - t) : 0;
  buf[t] = cnt;
  __syncthreads();
  for (int off = 1; off < S_; off <<= 1) {
    int v = buf[t];
    if (t >= off) v += buf[t - off];
    __syncthreads();
    buf[t] = v;
    __syncthreads();
  }
  int inc2 = buf[t];
  int base = inc2 - cnt;
  spoff[t] = base;
  if (t == 0) { meta[0] = buf[S_ - 1]; meta[1] = n; }
  __syncthreads();
  if (t < n) {
    int p0 = pos[t];
    for (int k = 0; k < cnt; k++) {
      starts[base + k] = p0;
      ends[base + k]   = pos[t + k];
      lens[base + k]   = k + 1;
    }
  }
}

// ---------------- fused prep: casts + transposes + LT + topicn ----------------
__global__ __launch_bounds__(256) void k_prep(
    const float* __restrict__ hid, bf16s* __restrict__ hidb,
    const float* __restrict__ W1, bf16s* __restrict__ wbt,
    const float* __restrict__ W2, bf16s* __restrict__ w2t, bf16s* __restrict__ w2c,
    const float* __restrict__ lemb, float* __restrict__ LT,
    const float* __restrict__ TH, const float* __restrict__ b2,
    bf16s* __restrict__ TN, float* __restrict__ cvec)
{
  __shared__ float tile[64][65];
  __shared__ float red[256];
  int bid = blockIdx.x;
  int t = threadIdx.x;
  if (bid < 12288) {
    int i = bid * 256 + t;           // BS*H/4 groups
    f32x4 v = ((const f32x4*)hid)[i];
    bf16x4 o;
    o[0] = (__bf16)v[0]; o[1] = (__bf16)v[1]; o[2] = (__bf16)v[2]; o[3] = (__bf16)v[3];
    ((bf16x4*)hidb)[i] = o;
  } else if (bid < 12864) {
    int local = bid - 12288;
    int c = local / 144, rem = local % 144;
    const float* in = (c < 3) ? (W1 + (size_t)c * H_ * H_) : W2;
    bf16s* out = (c < 3) ? (wbt + (size_t)c * H_ * H_) : w2t;
    int r0 = (rem / 12) * 64, c0 = (rem % 12) * 64;
    int tr = t >> 4, tc = (t & 15) * 4;
#pragma unroll
    for (int i = 0; i < 4; i++) {
      int row = tr + i * 16;
      f32x4 v = *(const f32x4*)(in + (long)(r0 + row) * H_ + c0 + tc);
      tile[row][tc+0] = v[0]; tile[row][tc+1] = v[1];
      tile[row][tc+2] = v[2]; tile[row][tc+3] = v[3];
    }
    __syncthreads();
#pragma unroll
    for (int i = 0; i < 4; i++) {
      int cc = tr + i * 16;
      bf16x4 o;
      o[0] = (__bf16)tile[tc+0][cc]; o[1] = (__bf16)tile[tc+1][cc];
      o[2] = (__bf16)tile[tc+2][cc]; o[3] = (__bf16)tile[tc+3][cc];
      *(bf16x4*)(out + (long)(c0 + cc) * H_ + r0 + tc) = o;
    }
  } else if (bid < 13440) {
    int i = (bid - 12864) * 256 + t;   // H*H/4 groups
    f32x4 v = ((const f32x4*)W2)[i];
    bf16x4 o;
    o[0] = (__bf16)v[0]; o[1] = (__bf16)v[1]; o[2] = (__bf16)v[2]; o[3] = (__bf16)v[3];
    ((bf16x4*)w2c)[i] = o;
  } else if (bid < 13455) {
    int idx = (bid - 13440) * 256 + t;
    if (idx < (L_ + 1) * H_) {
      int l = idx / H_, h = idx % H_;
      float acc = 0.f;
#pragma unroll
      for (int e = 0; e < LE_; e++) acc += lemb[l * LE_ + e] * W1[(long)(N3 + e) * H_ + h];
      LT[idx] = acc;
    }
  } else {
    int r = bid - 13455;               // topic row 0..1023
    const float* row = TH + (long)r * H_;
    float v0 = row[t], v1 = row[t + 256], v2 = row[t + 512];
    red[t] = v0 * v0 + v1 * v1 + v2 * v2;
    __syncthreads();
    for (int off = 128; off; off >>= 1) {
      if (t < off) red[t] += red[t + off];
      __syncthreads();
    }
    float rn = 1.0f / fmaxf(sqrtf(red[0]), 1e-12f);
    bf16s* o = TN + (long)r * H_;
    o[t] = (__bf16)(v0 * rn); o[t + 256] = (__bf16)(v1 * rn); o[t + 512] = (__bf16)(v2 * rn);
    __syncthreads();
    red[t] = v0 * b2[t] + v1 * b2[t + 256] + v2 * b2[t + 512];
    __syncthreads();
    for (int off = 128; off; off >>= 1) {
      if (t < off) red[t] += red[t + off];
      __syncthreads();
    }
    if (t == 0) cvec[r] = red[0] * rn;
  }
}

// ====== single-tile 8-phase GEMM core macros (BK=64, r5-proven) ======
#define BKT 64
#define STG1_A(kt_, h_) do { \
    const bf16s* s_ = gA + (long)(h_) * 128 * K + (long)(kt_) * BKT; \
    char* d_ = sA + ((kt_) & 1) * 32768 + (h_) * 16384 + wid * 1024; \
    gload_lds16(s_, d_); \
    gload_lds16(s_ + 64L * K, d_ + 8192); \
  } while (0)
#define STG1_B(kt_, h_) do { \
    const bf16s* s_ = gB + (long)(h_) * 128 * K + (long)(kt_) * BKT; \
    char* d_ = sB + ((kt_) & 1) * 32768 + (h_) * 16384 + wid * 1024; \
    gload_lds16(s_, d_); \
    gload_lds16(s_ + 64L * K, d_ + 8192); \
  } while (0)
#define MFMA_Q(AF_, FR0_, FC_) do { \
    _Pragma("unroll") \
    for (int f_ = 0; f_ < 4; ++f_) { \
      acc[FR0_+f_][FC_] = __builtin_amdgcn_mfma_f32_16x16x32_bf16(bfv[FC_][0], AF_[f_][0], acc[FR0_+f_][FC_], 0, 0, 0); \
      acc[FR0_+f_][FC_] = __builtin_amdgcn_mfma_f32_16x16x32_bf16(bfv[FC_][1], AF_[f_][1], acc[FR0_+f_][FC_], 0, 0, 0); \
    } } while (0)
#define PH_PRE()  __builtin_amdgcn_s_barrier(); \
                  asm volatile("s_waitcnt lgkmcnt(0)" ::: "memory"); \
                  __builtin_amdgcn_s_setprio(1)
#define PH_POST() __builtin_amdgcn_s_setprio(0); \
                  __builtin_amdgcn_s_barrier()

// ---- GEMM1 + U-GEMM (r9 config; 512 blocks, blocks 0..75 run 2 items) ----
__global__ __launch_bounds__(512, 2) void k_gemm8p(
    const bf16s* __restrict__ Ah, const bf16s* __restrict__ Bth, bf16s* __restrict__ Ch,
    const bf16s* __restrict__ Au, const bf16s* __restrict__ Btu, bf16s* __restrict__ Cu)
{
  __shared__ __align__(16) char sA[65536];
  __shared__ __align__(16) char sB[65536];
  const int K = H_;

  int tid = threadIdx.x;
  int wid = tid >> 6, l = tid & 63;
  int wr = wid >> 2, wc = wid & 3;          // 2x4 waves; wave tile 128x64
  int srow = tid >> 3;
  int sslot = (tid & 7) ^ (srow & 7);

  const char* aP0 = sA + wr * 16384;
  const char* aP1 = aP0 + 32768;
  const char* bP0 = sB + (wc >> 1) * 16384 + (wc & 1) * 8192;
  const char* bP1 = bP0 + 32768;
  int lrow = (l & 15) * 128;
  int ls0 = (((l >> 4) ^ (l & 7)) * 16);

  int nseg = (blockIdx.x < 76) ? 2 : 1;
#pragma unroll 1
  for (int seg = 0; seg < nseg; ++seg) {
    int raw = (seg == 0) ? blockIdx.x : 512 + blockIdx.x;
    const int nwg = 588;
    int q = nwg >> 3, rr = nwg & 7;
    int xcd = raw & 7, ix = raw >> 3;
    int nid = (xcd < rr ? xcd * (q + 1) : rr * (q + 1) + (xcd - rr) * q) + ix;

    const bf16s *A, *Bt;
    bf16s* C;
    long a0, b0;
    int NN;
    if (nid < 576) {
      A = Ah; Bt = Bth; C = Ch; NN = N3;
      a0 = (long)(nid / 9) * 256;
      b0 = (long)(nid % 9) * 256;
    } else {
      int u = nid - 576;
      A = Au; Bt = Btu; C = Cu; NN = H_;
      a0 = (long)(u / 3) * 256;
      b0 = (long)(u % 3) * 256;
    }
    const bf16s* gA = A + (a0 + srow) * (long)K + sslot * 8;
    const bf16s* gB = Bt + (b0 + srow) * (long)K + sslot * 8;

    f32x4 acc[8][4];
#pragma unroll
    for (int i = 0; i < 8; i++)
#pragma unroll
      for (int j = 0; j < 4; j++) acc[i][j] = (f32x4){0.f, 0.f, 0.f, 0.f};

    STG1_B(0, 0); STG1_B(0, 1); STG1_A(0, 0); STG1_A(0, 1);
    STG1_B(1, 0); STG1_B(1, 1); STG1_A(1, 0);
    asm volatile("s_waitcnt vmcnt(6)" ::: "memory");
    __builtin_amdgcn_s_barrier();

    for (int it = 0; it < 6; ++it) {
      int t0 = 2 * it, t1 = t0 + 1;
      bool nl = (it != 5);
      bf16x8 af0[4][2], af1[4][2], bfv[4][2];

#pragma unroll
      for (int f = 0; f < 4; ++f) {
        af0[f][0] = *(const bf16x8*)(aP0 + f * 2048 + lrow + ls0);
        af0[f][1] = *(const bf16x8*)(aP0 + f * 2048 + lrow + (ls0 ^ 64));
      }
#pragma unroll
      for (int c = 0; c < 4; ++c) {
        bfv[c][0] = *(const bf16x8*)(bP0 + c * 2048 + lrow + ls0);
        bfv[c][1] = *(const bf16x8*)(bP0 + c * 2048 + lrow + (ls0 ^ 64));
      }
      STG1_A(t1, 1);
      PH_PRE();
      MFMA_Q(af0, 0, 0); MFMA_Q(af0, 0, 1);
      PH_POST();

      if (nl) STG1_B(t0 + 2, 0);
      PH_PRE();
      MFMA_Q(af0, 0, 2); MFMA_Q(af0, 0, 3);
      PH_POST();

#pragma unroll
      for (int f = 0; f < 4; ++f) {
        af1[f][0] = *(const bf16x8*)(aP0 + (f + 4) * 2048 + lrow + ls0);
        af1[f][1] = *(const bf16x8*)(aP0 + (f + 4) * 2048 + lrow + (ls0 ^ 64));
      }
      if (nl) STG1_B(t0 + 2, 1);
      PH_PRE();
      MFMA_Q(af1, 4, 0); MFMA_Q(af1, 4, 1);
      PH_POST();

      if (nl) { STG1_A(t0 + 2, 0); asm volatile("s_waitcnt vmcnt(6)" ::: "memory"); }
      else    { asm volatile("s_waitcnt vmcnt(0)" ::: "memory"); }
      PH_PRE();
      MFMA_Q(af1, 4, 2); MFMA_Q(af1, 4, 3);
      PH_POST();

#pragma unroll
      for (int f = 0; f < 4; ++f) {
        af0[f][0] = *(const bf16x8*)(aP1 + f * 2048 + lrow + ls0);
        af0[f][1] = *(const bf16x8*)(aP1 + f * 2048 + lrow + (ls0 ^ 64));
      }
#pragma unroll
      for (int c = 0; c < 4; ++c) {
        bfv[c][0] = *(const bf16x8*)(bP1 + c * 2048 + lrow + ls0);
        bfv[c][1] = *(const bf16x8*)(bP1 + c * 2048 + lrow + (ls0 ^ 64));
      }
      if (nl) STG1_A(t0 + 2, 1);
      PH_PRE();
      MFMA_Q(af0, 0, 0); MFMA_Q(af0, 0, 1);
      PH_POST();

      if (nl) STG1_B(t1 + 2, 0);
      PH_PRE();
      MFMA_Q(af0, 0, 2); MFMA_Q(af0, 0, 3);
      PH_POST();

#pragma unroll
      for (int f = 0; f < 4; ++f) {
        af1[f][0] = *(const bf16x8*)(aP1 + (f + 4) * 2048 + lrow + ls0);
        af1[f][1] = *(const bf16x8*)(aP1 + (f + 4) * 2048 + lrow + (ls0 ^ 64));
      }
      if (nl) STG1_B(t1 + 2, 1);
      PH_PRE();
      MFMA_Q(af1, 4, 0); MFMA_Q(af1, 4, 1);
      PH_POST();

      if (nl) { STG1_A(t1 + 2, 0); asm volatile("s_waitcnt vmcnt(6)" ::: "memory"); }
      else    { asm volatile("s_waitcnt vmcnt(0)" ::: "memory"); }
      PH_PRE();
      MFMA_Q(af1, 4, 2); MFMA_Q(af1, 4, 3);
      PH_POST();
    }

#pragma unroll
    for (int fc = 0; fc < 4; fc++) {
      long n0 = b0 + wc * 64 + fc * 16 + (l >> 4) * 4;
#pragma unroll
      for (int fr = 0; fr < 8; fr++) {
        long mrow = a0 + wr * 128 + fr * 16 + (l & 15);
        bf16x4 o;
#pragma unroll
        for (int r = 0; r < 4; r++) o[r] = (__bf16)acc[fr][fc][r];
        *(bf16x4*)(C + mrow * (long)NN + n0) = o;
      }
    }
  }
}

// ====== chained 3-segment core for gemmnorm (r8-proven, 256x256, BK=64) ======
#define STG_A(kt_, h_) do { \
    const bf16s* s_ = gA + (long)(h_) * 128 * K + (long)(kt_) * BKT; \
    char* d_ = sA + ((kt_) & 1) * 32768 + (h_) * 16384 + wid * 1024; \
    gload_lds16(s_, d_); \
    gload_lds16(s_ + 64L * K, d_ + 8192); \
  } while (0)
#define STG_B(ct_, kt_, h_) do { \
    const bf16s* s_ = gB + (long)(ct_) * 256 * K + (long)(h_) * 128 * K + (long)(kt_) * BKT; \
    char* d_ = sB + ((kt_) & 1) * 32768 + (h_) * 16384 + wid * 1024; \
    gload_lds16(s_, d_); \
    gload_lds16(s_ + 64L * K, d_ + 8192); \
  } while (0)

#define CHAIN_CORE(EPILOG_) \
  const char* aP0 = sA + wr * 16384; \
  const char* aP1 = aP0 + 32768; \
  const char* bP0 = sB + (wc >> 1) * 16384 + (wc & 1) * 8192; \
  const char* bP1 = bP0 + 32768; \
  int lrow = (l & 15) * 128; \
  int ls0 = (((l >> 4) ^ (l & 7)) * 16); \
  f32x4 acc[8][4]; \
  _Pragma("unroll") \
  for (int i_ = 0; i_ < 8; i_++) \
    _Pragma("unroll") \
    for (int j_ = 0; j_ < 4; j_++) acc[i_][j_] = (f32x4){0.f, 0.f, 0.f, 0.f}; \
  STG_B(0, 0, 0); STG_B(0, 0, 1); STG_A(0, 0); STG_A(0, 1); \
  STG_B(0, 1, 0); STG_B(0, 1, 1); STG_A(1, 0); \
  asm volatile("s_waitcnt vmcnt(6)" ::: "memory"); \
  __builtin_amdgcn_s_barrier(); \
  for (int s = 0; s < 3; ++s) { \
    for (int it = 0; it < 6; ++it) { \
      int kt0 = 2 * it; \
      bool nl = !(s == 2 && it == 5); \
      int ctn = (it == 5) ? s + 1 : s; \
      int kn0 = (it == 5) ? 0 : kt0 + 2; \
      int kn1 = (it == 5) ? 1 : kt0 + 3; \
      bf16x8 af0[4][2], af1[4][2], bfv[4][2]; \
      _Pragma("unroll") \
      for (int f = 0; f < 4; ++f) { \
        af0[f][0] = *(const bf16x8*)(aP0 + f * 2048 + lrow + ls0); \
        af0[f][1] = *(const bf16x8*)(aP0 + f * 2048 + lrow + (ls0 ^ 64)); \
      } \
      _Pragma("unroll") \
      for (int c = 0; c < 4; ++c) { \
        bfv[c][0] = *(const bf16x8*)(bP0 + c * 2048 + lrow + ls0); \
        bfv[c][1] = *(const bf16x8*)(bP0 + c * 2048 + lrow + (ls0 ^ 64)); \
      } \
      STG_A(kt0 + 1, 1); \
      PH_PRE(); \
      MFMA_Q(af0, 0, 0); MFMA_Q(af0, 0, 1); \
      PH_POST(); \
      if (nl) STG_B(ctn, kn0, 0); \
      PH_PRE(); \
      MFMA_Q(af0, 0, 2); MFMA_Q(af0, 0, 3); \
      PH_POST(); \
      _Pragma("unroll") \
      for (int f = 0; f < 4; ++f) { \
        af1[f][0] = *(const bf16x8*)(aP0 + (f + 4) * 2048 + lrow + ls0); \
        af1[f][1] = *(const bf16x8*)(aP0 + (f + 4) * 2048 + lrow + (ls0 ^ 64)); \
      } \
      if (nl) STG_B(ctn, kn0, 1); \
      PH_PRE(); \
      MFMA_Q(af1, 4, 0); MFMA_Q(af1, 4, 1); \
      PH_POST(); \
      if (nl) { STG_A(kn0, 0); asm volatile("s_waitcnt vmcnt(6)" ::: "memory"); } \
      else    { asm volatile("s_waitcnt vmcnt(0)" ::: "memory"); } \
      PH_PRE(); \
      MFMA_Q(af1, 4, 2); MFMA_Q(af1, 4, 3); \
      PH_POST(); \
      _Pragma("unroll") \
      for (int f = 0; f < 4; ++f) { \
        af0[f][0] = *(const bf16x8*)(aP1 + f * 2048 + lrow + ls0); \
        af0[f][1] = *(const bf16x8*)(aP1 + f * 2048 + lrow + (ls0 ^ 64)); \
      } \
      _Pragma("unroll") \
      for (int c = 0; c < 4; ++c) { \
        bfv[c][0] = *(const bf16x8*)(bP1 + c * 2048 + lrow + ls0); \
        bfv[c][1] = *(const bf16x8*)(bP1 + c * 2048 + lrow + (ls0 ^ 64)); \
      } \
      if (nl) STG_A(kn0, 1); \
      PH_PRE(); \
      MFMA_Q(af0, 0, 0); MFMA_Q(af0, 0, 1); \
      PH_POST(); \
      if (nl) STG_B(ctn, kn1, 0); \
      PH_PRE(); \
      MFMA_Q(af0, 0, 2); MFMA_Q(af0, 0, 3); \
      PH_POST(); \
      _Pragma("unroll") \
      for (int f = 0; f < 4; ++f) { \
        af1[f][0] = *(const bf16x8*)(aP1 + (f + 4) * 2048 + lrow + ls0); \
        af1[f][1] = *(const bf16x8*)(aP1 + (f + 4) * 2048 + lrow + (ls0 ^ 64)); \
      } \
      if (nl) STG_B(ctn, kn1, 1); \
      PH_PRE(); \
      MFMA_Q(af1, 4, 0); MFMA_Q(af1, 4, 1); \
      PH_POST(); \
      if (nl) { STG_A(kn1, 0); asm volatile("s_waitcnt vmcnt(6)" ::: "memory"); } \
      else    { asm volatile("s_waitcnt vmcnt(0)" ::: "memory"); } \
      PH_PRE(); \
      MFMA_Q(af1, 4, 2); MFMA_Q(af1, 4, 3); \
      PH_POST(); \
    } \
    EPILOG_(s); \
  }

// ---- chained norm-only GEMM: ssbuf[row] = sum over 768 cols of (X@W2^T + b2)^2 ----
__global__ __launch_bounds__(512, 1) void k_gemmnorm(
    const bf16s* __restrict__ Ax, const bf16s* __restrict__ Btw,
    const float* __restrict__ bias, float* __restrict__ ssbuf)
{
  __shared__ __align__(16) char sA[65536];
  __shared__ __align__(16) char sB[65536];
  const int K = H_;
  int bid = blockIdx.x;
  int nid = (bid & 7) * 32 + (bid >> 3);     // 256 blocks = 1 mt each
  long a0 = (long)nid * 256;
  long b0base = 0;
  int tid = threadIdx.x;
  int wid = tid >> 6, l = tid & 63;
  int wr = wid >> 2, wc = wid & 3;
  int srow = tid >> 3;
  int sslot = (tid & 7) ^ (srow & 7);
  const bf16s* gA = Ax + (a0 + srow) * (long)K + sslot * 8;
  const bf16s* gB = Btw + (b0base + srow) * (long)K + sslot * 8;
  float ssp[8] = {0.f, 0.f, 0.f, 0.f, 0.f, 0.f, 0.f, 0.f};

#define EPI_N(s_) do { \
    f32x4 bb[4]; \
    _Pragma("unroll") \
    for (int fc = 0; fc < 4; ++fc) \
      bb[fc] = *(const f32x4*)(bias + (s_) * 256 + wc * 64 + fc * 16 + (l >> 4) * 4); \
    _Pragma("unroll") \
    for (int fr = 0; fr < 8; ++fr) { \
      float p = 0.f; \
      _Pragma("unroll") \
      for (int fc = 0; fc < 4; ++fc) { \
        _Pragma("unroll") \
        for (int r = 0; r < 4; ++r) { \
          float y = acc[fr][fc][r] + bb[fc][r]; \
          p += y * y; \
        } \
        acc[fr][fc] = (f32x4){0.f, 0.f, 0.f, 0.f}; \
      } \
      ssp[fr] += p; \
    } \
  } while (0)

  CHAIN_CORE(EPI_N)
#undef EPI_N

  // cross-wave reduction: 4 wc-waves hold partial column-slice sums per row.
  float* sred = (float*)sA;
#pragma unroll
  for (int fr = 0; fr < 8; ++fr) {
    float p = ssp[fr];
    p += __shfl_xor(p, 16);
    p += __shfl_xor(p, 32);
    if (l < 16) sred[wc * 256 + wr * 128 + fr * 16 + l] = p;
  }
  __syncthreads();
  if (tid < 256) {
    ssbuf[a0 + tid] = sred[tid] + sred[256 + tid] + sred[512 + tid] + sred[768 + tid];
  }
}

#undef CHAIN_CORE
#undef STG_A
#undef STG_B
#undef STG1_A
#undef STG1_B
#undef MFMA_Q
#undef PH_PRE
#undef PH_POST

// ---------------- z1: per (batch, start-pos) group, running-sum mean ----------
__global__ __launch_bounds__(192) void k_z1(
    const bf16s* __restrict__ P,
    const float* __restrict__ LT, const float* __restrict__ b1,
    const int* __restrict__ pos, const int* __restrict__ spoff,
    const int* __restrict__ meta, bf16s* __restrict__ X)
{
  int bid = blockIdx.x;
  int t = threadIdx.x;            // 0..191
  int h = t * 4;
  if (bid < BS) {
    int b = bid >> 10, i = bid & (S_ - 1);
    int n = meta[1];
    if (i >= n) return;
    int cnt = min(L_, n - i);
    int sa = pos[i];
    int base = spoff[i];
    const bf16s* Pb = P + (long)b * S_ * N3;
    bf16x4 vs = *(const bf16x4*)(Pb + (long)sa * N3 + h);
    f32x4 bb = *(const f32x4*)(b1 + h);
    float run[4] = {0.f, 0.f, 0.f, 0.f};
    int r = sa;
    for (int k = 0; k < cnt; ++k) {
      int se = pos[i + k];
      for (; r <= se; ++r) {
        bf16x4 vm = *(const bf16x4*)(Pb + (long)r * N3 + 2 * H_ + h);
#pragma unroll
        for (int j = 0; j < 4; j++) run[j] += (float)vm[j];
      }
      bf16x4 ve = *(const bf16x4*)(Pb + (long)se * N3 + H_ + h);
      f32x4 lt = *(const f32x4*)(LT + (long)(k + 1) * H_ + h);
      float il = 1.0f / (float)(k + 1);
      bf16x4 o;
#pragma unroll
      for (int j = 0; j < 4; j++) {
        float x = (float)vs[j] + (float)ve[j] + run[j] * il + lt[j] + bb[j];
        float g = 0.5f * x * (1.0f + erff(x * 0.70710678118654752f));
        o[j] = (__bf16)g;
      }
      *(bf16x4*)(X + ((long)b * NPAD + base + k) * H_ + h) = o;
    }
  } else {
    // zero-fill pad rows [N, NPAD) across all batches (grid-stride)
    int N = meta[0];
    int pad = NPAD - N;
    if (pad <= 0) return;
    long total = (long)B_ * pad * 192;
    for (long idx = (long)(bid - BS) * 192 + t; idx < total; idx += 512L * 192) {
      int h4 = (int)(idx % 192);
      long rrw = idx / 192;
      int pr = (int)(rrw % pad);
      int bb2 = (int)(rrw / pad);
      bf16x4 z; z[0] = z[1] = z[2] = z[3] = (__bf16)0.f;
      *(bf16x4*)(X + ((long)bb2 * NPAD + N + pr) * H_ + h4 * 4) = z;
    }
  }
}

// ------- sim from X: scores[b,n] = max_t (U[t]·X_n + c[t]) * rsqrt(ss[n]) ----
__global__ __launch_bounds__(256) void k_simx(
    const bf16s* __restrict__ X, const bf16s* __restrict__ U,
    const float* __restrict__ cvec, const float* __restrict__ ssbuf,
    const int* __restrict__ tmask, float* __restrict__ scores)
{
  int b = blockIdx.y;
  int wid = threadIdx.x >> 6, l = threadIdx.x & 63;
  int st = blockIdx.x * 4 + wid;
  int span = st * 16 + (l & 15);
  const bf16s* xrow = X + (long)(b * NPAD + span) * H_ + (l >> 4) * 8;
  const bf16s* ubase = U + (long)b * T_ * H_ + (l >> 4) * 8;
  f32x4 acc[4];
#pragma unroll
  for (int tt = 0; tt < 4; tt++) acc[tt] = (f32x4){0.f, 0.f, 0.f, 0.f};
  for (int kk = 0; kk < H_ / 32; kk++) {
    bf16x8 av = *(const bf16x8*)(xrow + kk * 32);
#pragma unroll
    for (int tt = 0; tt < 4; tt++) {
      bf16x8 bv = *(const bf16x8*)(ubase + (long)(tt * 16 + (l & 15)) * H_ + kk * 32);
      acc[tt] = __builtin_amdgcn_mfma_f32_16x16x32_bf16(av, bv, acc[tt], 0, 0, 0);
    }
  }
  const int* tm = tmask + b * T_;
  bool msk[4];
  float cv[4];
#pragma unroll
  for (int tt = 0; tt < 4; tt++) {
    int tcol = tt * 16 + (l & 15);
    msk[tt] = tm[tcol] != 0;
    cv[tt] = cvec[b * T_ + tcol];
  }
  float best[4];
#pragma unroll
  for (int r = 0; r < 4; r++) {
    float v = -INFINITY;
#pragma unroll
    for (int tt = 0; tt < 4; tt++) if (msk[tt]) v = fmaxf(v, acc[tt][r] + cv[tt]);
    best[r] = v;
  }
#pragma unroll
  for (int off = 8; off; off >>= 1)
#pragma unroll
    for (int r = 0; r < 4; r++) best[r] = fmaxf(best[r], __shfl_xor(best[r], off));
  if ((l & 15) == 0) {
    int srow = st * 16 + (l >> 4) * 4;
#pragma unroll
    for (int r = 0; r < 4; r++) {
      float ss = ssbuf[b * NPAD + srow + r];
      scores[b * NPAD + srow + r] = best[r] / fmaxf(sqrtf(ss), 1e-12f);
    }
  }
}

// ---------------- token max ----------------
__global__ __launch_bounds__(256) void k_token(
    const int* __restrict__ text_mask,
    const int* __restrict__ R, const int* __restrict__ spoff,
    const int* __restrict__ meta, const float* __restrict__ scores,
    float* __restrict__ out)
{
  int idx = blockIdx.x * 256 + threadIdx.x;  // B*S
  int s = idx % S_, b = idx / S_;
  if (!text_mask[b * S_ + s]) { out[idx] = -INFINITY; return; }
  int n = meta[1];
  int r1 = R[s];
  int le = r1 - 1;                         // largest i with pos[i] <= s
  int ge = text_mask[s] ? (r1 - 1) : r1;   // smallest j with pos[j] >= s (row 0)
  float best = -INFINITY;
  if (le >= 0 && ge < n) {
    int i0 = max(0, ge - (L_ - 1));
    for (int i = i0; i <= le; i++) {
      int jmax = min(i + L_ - 1, n - 1);
      int off = spoff[i];
      for (int j = max(i, ge); j <= jmax; j++)
        best = fmaxf(best, scores[b * NPAD + off + (j - i)]);
    }
  }
  out[idx] = best;
}

// ---------------- ws-too-small sentinel ----------------
__global__ __launch_bounds__(256) void k_sentinel(float* __restrict__ out) {
  int i = blockIdx.x * 256 + threadIdx.x;
  if (i < BS) out[i] = 12345.0f;
}

// ---------------- launch ----------------
extern "C" void kernel_launch(void* const* d_in, const int* in_sizes, int n_in,
                              void* d_out, int out_size, void* d_ws, size_t ws_size,
                              hipStream_t stream) {
  const float* hid = (const float*)d_in[0];
  const float* th  = (const float*)d_in[1];
  const int* tmask = (const int*)d_in[2];
  const int* xmask = (const int*)d_in[3];
  const float* lemb = (const float*)d_in[4];
  const float* W1   = (const float*)d_in[5];
  const float* b1   = (const float*)d_in[6];
  const float* W2   = (const float*)d_in[7];
  const float* b2   = (const float*)d_in[8];
  float* out = (float*)d_out;

  char* w = (char*)d_ws;
  auto alloc = [&](size_t bytes) {
    char* p = w; w += (bytes + 255) & ~(size_t)255; return p;
  };
  // small buffers (~10 MB)
  bf16s* wbt   = (bf16s*)alloc((size_t)N3 * H_ * 2);
  bf16s* w2t   = (bf16s*)alloc((size_t)H_ * H_ * 2);
  bf16s* w2c   = (bf16s*)alloc((size_t)H_ * H_ * 2);
  float* LT    = (float*)alloc((size_t)(L_ + 1) * H_ * 4);
  bf16s* topn  = (bf16s*)alloc((size_t)B_ * T_ * H_ * 2);
  bf16s* U     = (bf16s*)alloc((size_t)B_ * T_ * H_ * 2);
  float* cvec  = (float*)alloc((size_t)B_ * T_ * 4);
  float* ssbuf = (float*)alloc((size_t)BNR * 4);
  float* scores= (float*)alloc((size_t)B_ * NPAD * 4);
  int* R       = (int*)alloc(S_ * 4);
  int* pos     = (int*)alloc(S_ * 4);
  int* spoff   = (int*)alloc(S_ * 4);
  int* starts  = (int*)alloc(NPAD * 4);
  int* ends    = (int*)alloc(NPAD * 4);
  int* lens    = (int*)alloc(NPAD * 4);
  int* meta    = (int*)alloc(2 * 4);
  // region A: [hidb | P] (100.66 MB)
  char* regionA = alloc((size_t)BS * H_ * 2 + (size_t)BS * N3 * 2);
  bf16s* hidb  = (bf16s*)regionA;
  bf16s* P     = (bf16s*)(regionA + (size_t)BS * H_ * 2);
  // region B: X (100.66 MB)
  bf16s* X     = (bf16s*)alloc((size_t)BNR * H_ * 2);

  size_t required = (size_t)(w - (char*)d_ws);
  if (required > ws_size) {
    k_sentinel<<<(BS + 255) / 256, 256, 0, stream>>>(out);
    return;
  }

  k_build_spans<<<1, 1024, 0, stream>>>(xmask, R, pos, spoff, starts, ends, lens, meta);
  k_prep<<<14479, 256, 0, stream>>>(hid, hidb, W1, wbt, W2, w2t, w2c,
                                    lemb, LT, th, b2, topn, cvec);

  // GEMM1 (576 P-tiles) + U-GEMM (12 tiles) over 512 blocks, <=2 items each
  k_gemm8p<<<512, 512, 0, stream>>>(hidb, wbt, P, topn, w2c, U);

  k_z1<<<BS + 512, 192, 0, stream>>>(P, LT, b1, pos, spoff, meta, X);

  // norm-only GEMM2 chained over all 768 cols: ssbuf = rowwise ||X@W2^T + b2||^2
  k_gemmnorm<<<256, 512, 0, stream>>>(X, w2t, b2, ssbuf);

  k_simx<<<dim3(NPAD / 64, B_), 256, 0, stream>>>(X, U, cvec, ssbuf, tmask, scores);
  k_token<<<(B_ * S_) / 256, 256, 0, stream>>>(xmask, R, spoff, meta, scores, out);
  (void)in_sizes; (void)n_in; (void)out_size;
}